// Round 11
// baseline (323.156 us; speedup 1.0000x reference)
//
#include <hip/hip_runtime.h>
#include <hip/hip_bf16.h>
#include <math.h>

#define BS 1024
#define D 128
#define NP 100000
#define PROWS 100096              // padded to multiple of 128 (96 zero rows)
#define CH 128                    // proxies per chunk/block
#define NCH (PROWS / CH)          // 782
#define NSLICE 16                 // rowsum slices (atomic contention / 16)
#define LOG2E 1.44269504088896340736f

typedef float f32x4 __attribute__((ext_vector_type(4)));
typedef __bf16 bf16x8 __attribute__((ext_vector_type(8)));
typedef unsigned short u16x8 __attribute__((ext_vector_type(8)));

#if defined(__has_builtin)
#if __has_builtin(__builtin_amdgcn_exp2f)
#define FAST_EXP2(x) __builtin_amdgcn_exp2f(x)
#endif
#endif
#ifndef FAST_EXP2
#define FAST_EXP2(x) exp2f(x)
#endif

static __device__ __forceinline__ unsigned short f2bf(float x) {
    unsigned int u = __float_as_uint(x);
    return (unsigned short)((u + 0x7fffu + ((u >> 16) & 1u)) >> 16);  // RNE
}

// ---------- kernel 1: batch -> bf16 A, d_pos; zero rowsum slices + counter -
__global__ __launch_bounds__(256) void prep_kernel(
    const float* __restrict__ batch, const float* __restrict__ proxies,
    const int* __restrict__ labels, unsigned short* __restrict__ A,
    float* __restrict__ d_pos, float* __restrict__ rowsum,
    unsigned int* __restrict__ counter)
{
    if (threadIdx.x < 128) rowsum[blockIdx.x * 128 + threadIdx.x] = 0.f;
    if (blockIdx.x == 0 && threadIdx.x == 0) *counter = 0u;

    int wave = threadIdx.x >> 6, lane = threadIdx.x & 63;
    int sub = lane >> 5, c = lane & 31;
    int row = blockIdx.x * 8 + wave * 2 + sub;   // 0..1023
    float4 v = *(const float4*)(batch + (size_t)row * D + c * 4);
    float ss = v.x*v.x + v.y*v.y + v.z*v.z + v.w*v.w;
    #pragma unroll
    for (int m = 1; m < 32; m <<= 1) ss += __shfl_xor(ss, m, 64);
    float sc = 3.0f / fmaxf(sqrtf(ss), 1e-12f);
    ushort4 pk;
    pk.x = f2bf(v.x*sc); pk.y = f2bf(v.y*sc);
    pk.z = f2bf(v.z*sc); pk.w = f2bf(v.w*sc);
    *(ushort4*)(A + (size_t)row * D + c * 4) = pk;
    // d_pos in fp32: 18 - 2*(b.p_label)
    int lab = labels[row];
    float4 p4 = *(const float4*)(proxies + (size_t)lab * D + c * 4);
    float ps = p4.x*p4.x + p4.y*p4.y + p4.z*p4.z + p4.w*p4.w;
    #pragma unroll
    for (int m = 1; m < 32; m <<= 1) ps += __shfl_xor(ps, m, 64);
    float psc = 3.0f / fmaxf(sqrtf(ps), 1e-12f);
    float dt = (v.x*sc)*(p4.x*psc) + (v.y*sc)*(p4.y*psc)
             + (v.z*sc)*(p4.z*psc) + (v.w*sc)*(p4.w*psc);
    #pragma unroll
    for (int m = 1; m < 32; m <<= 1) dt += __shfl_xor(dt, m, 64);
    if (c == 0) d_pos[row] = 18.0f - 2.0f * dt;
}

// ---------- kernel 2: fused proxy-norm + GEMM + exp + final ----------------
// 256 threads (4 waves), block = 128 proxies (two-pass staged into XOR-
// swizzled LDS bf16). INVERTED caching: each wave register-caches the
// GLOBAL-sourced B operand (Bf[4][4] = 64 batch rows x K=128, 64 VGPRs,
// loaded once per row-set from L2) and STREAMS A from LDS: per proxy
// M-tile only 4 ds_read_b128 feed 16 MFMAs (4x reuse). acc[4] recycled
// per M-tile into per-batch-row exp-sums rs[4] (proxy dim = C-tile rows
// -> in-lane + 2 shuffles). 4 row-sets of 64 cover all 1024 batch rows.
__global__ __launch_bounds__(256, 3) void main_kernel(
    const float* __restrict__ proxies,
    const unsigned short* __restrict__ Abat,
    float* __restrict__ rowsum,          // [NSLICE][BS]
    const float* __restrict__ d_pos,
    float* __restrict__ out,
    unsigned int* __restrict__ counter)
{
    __shared__ unsigned short Plds[CH * D];   // 32 KB
    __shared__ float shf[4];
    __shared__ unsigned int is_last;
    const int tid = threadIdx.x;
    const int lane = tid & 63;
    const int wave = tid >> 6, quad = lane >> 4, l15 = lane & 15;
    const int chunk = blockIdx.x;

    // ---- staging: r = tid>>1 (0..127), h = tid&1 (64 floats each) --------
    {
        int r = tid >> 1, h = tid & 1;
        int pidx = chunk * CH + r;
        const float* src = proxies + (size_t)pidx * D + h * 64;
        float ss = 0.f;
        if (pidx < NP) {
            #pragma unroll
            for (int j = 0; j < 16; ++j) {
                float4 v = *(const float4*)(src + j * 4);
                ss += v.x*v.x + v.y*v.y + v.z*v.z + v.w*v.w;
            }
        }
        ss += __shfl_xor(ss, 1, 64);             // combine the two halves
        float sc = 3.0f / fmaxf(sqrtf(ss), 1e-12f);
        #pragma unroll
        for (int j = 0; j < 8; ++j) {
            u16x8 w = (u16x8){0,0,0,0,0,0,0,0};
            if (pidx < NP) {
                float4 a = *(const float4*)(src + j * 8);      // L2 hit
                float4 b = *(const float4*)(src + j * 8 + 4);
                w[0] = f2bf(a.x*sc); w[1] = f2bf(a.y*sc);
                w[2] = f2bf(a.z*sc); w[3] = f2bf(a.w*sc);
                w[4] = f2bf(b.x*sc); w[5] = f2bf(b.y*sc);
                w[6] = f2bf(b.z*sc); w[7] = f2bf(b.w*sc);
            }
            int cl = h * 8 + j;                  // 16B chunk index in row
            *(u16x8*)((char*)Plds + r * 256 + ((cl ^ (r & 15)) << 4)) = w;
        }
    }
    __syncthreads();

    const float c1 = 2.0f * LOG2E, c0 = -18.0f * LOG2E;
    float* rs_base = rowsum + (size_t)(chunk & (NSLICE - 1)) * BS;

    #pragma unroll 1
    for (int set = 0; set < 4; ++set) {
        const int row0 = wave * 256 + set * 64;      // this set's 64 rows
        const unsigned short* ab = Abat + (size_t)(row0 + l15) * D + quad * 8;

        // register-cache B: 64 batch rows x K=128 (16 global dwordx4, L2)
        bf16x8 Bf[4][4];
        #pragma unroll
        for (int ng = 0; ng < 4; ++ng)
            #pragma unroll
            for (int kk = 0; kk < 4; ++kk)
                Bf[ng][kk] = *(const bf16x8*)(ab + (size_t)ng * 16 * D + kk * 32);

        float rs[4] = {0.f, 0.f, 0.f, 0.f};

        #pragma unroll
        for (int mt = 0; mt < 8; ++mt) {
            // stream A fragments for this 16-proxy tile: 4 ds_read_b128
            f32x4 Af[4];
            int prow = mt * 16 + l15;
            #pragma unroll
            for (int kk = 0; kk < 4; ++kk) {
                int cl = kk * 4 + quad;
                Af[kk] = *(const f32x4*)((const char*)Plds + prow * 256
                                         + ((cl ^ (prow & 15)) << 4));
            }
            f32x4 acc[4];
            #pragma unroll
            for (int ng = 0; ng < 4; ++ng) acc[ng] = (f32x4){0.f, 0.f, 0.f, 0.f};
            #pragma unroll
            for (int kk = 0; kk < 4; ++kk)
                #pragma unroll
                for (int ng = 0; ng < 4; ++ng)
                    acc[ng] = __builtin_amdgcn_mfma_f32_16x16x32_bf16(
                        __builtin_bit_cast(bf16x8, Af[kk]), Bf[ng][kk],
                        acc[ng], 0, 0, 0);
            // fold this tile's 4 proxy rows (per lane) into the row-sums
            #pragma unroll
            for (int ng = 0; ng < 4; ++ng) {
                float e0 = FAST_EXP2(fmaf(acc[ng][0], c1, c0));
                float e1 = FAST_EXP2(fmaf(acc[ng][1], c1, c0));
                float e2 = FAST_EXP2(fmaf(acc[ng][2], c1, c0));
                float e3 = FAST_EXP2(fmaf(acc[ng][3], c1, c0));
                rs[ng] += (e0 + e1) + (e2 + e3);
            }
        }
        // reduce over quads (proxy rows) and commit
        #pragma unroll
        for (int ng = 0; ng < 4; ++ng) {
            float v = rs[ng];
            v += __shfl_xor(v, 16, 64);
            v += __shfl_xor(v, 32, 64);
            if (quad == 0)
                atomicAdd(rs_base + row0 + ng * 16 + l15, v);
        }
    }

    // ---- last-block-done: final lse + mean ------------------------------
    __syncthreads();
    if (tid == 0) {
        __threadfence();
        unsigned int old = __hip_atomic_fetch_add(counter, 1u,
                              __ATOMIC_ACQ_REL, __HIP_MEMORY_SCOPE_AGENT);
        is_last = (old == NCH - 1) ? 1u : 0u;
    }
    __syncthreads();
    if (is_last) {
        const float PADC = 96.0f * exp2f(-18.0f * LOG2E);  // zero-pad rows
        float accv = 0.f;
        #pragma unroll
        for (int i = 0; i < 4; ++i) {
            int row = tid * 4 + i;     // 0..1023
            float tot = 0.f;
            #pragma unroll
            for (int s = 0; s < NSLICE; ++s)
                tot += __hip_atomic_load(&rowsum[(size_t)s * BS + row],
                          __ATOMIC_RELAXED, __HIP_MEMORY_SCOPE_AGENT);
            float dp = d_pos[row];
            float neg = tot - expf(-dp) - PADC;            // drop own column
            accv += dp + logf(fmaxf(neg, 1e-37f));
        }
        #pragma unroll
        for (int m = 1; m < 64; m <<= 1) accv += __shfl_xor(accv, m, 64);
        if ((tid & 63) == 0) shf[tid >> 6] = accv;
        __syncthreads();
        if (tid == 0)
            out[0] = (shf[0] + shf[1] + shf[2] + shf[3]) * (1.0f / 1024.0f);
    }
}

extern "C" void kernel_launch(void* const* d_in, const int* in_sizes, int n_in,
                              void* d_out, int out_size, void* d_ws, size_t ws_size,
                              hipStream_t stream) {
    const float* batch   = (const float*)d_in[0];
    const float* proxies = (const float*)d_in[1];
    const int*   labels  = (const int*)d_in[2];
    float* out = (float*)d_out;

    char* ws = (char*)d_ws;
    unsigned short* A    = (unsigned short*)ws;                  //   262,144 B
    float* d_pos         = (float*)(ws + 262144);                //     4,096 B
    float* rowsum        = (float*)(ws + 266240);                //    65,536 B
    unsigned int* counter= (unsigned int*)(ws + 331776);         //         4 B

    prep_kernel<<<128, 256, 0, stream>>>(batch, proxies, labels, A, d_pos,
                                         rowsum, counter);
    main_kernel<<<NCH, 256, 0, stream>>>(proxies, A, rowsum, d_pos, out, counter);
}

// Round 12
// 187.795 us; speedup vs baseline: 1.7208x; 1.7208x over previous
//
#include <hip/hip_runtime.h>
#include <hip/hip_bf16.h>
#include <math.h>

#define BS 1024
#define D 128
#define NP 100000
#define PROWS 100096              // padded to multiple of 128 (96 zero rows)
#define CH 128                    // proxies per chunk/block
#define NCH (PROWS / CH)          // 782
#define NSLICE 16                 // rowsum slices (atomic contention / 16)
#define LOG2E 1.44269504088896340736f

typedef float f32x4 __attribute__((ext_vector_type(4)));
typedef __bf16 bf16x8 __attribute__((ext_vector_type(8)));
typedef unsigned short u16x8 __attribute__((ext_vector_type(8)));

#if defined(__has_builtin)
#if __has_builtin(__builtin_amdgcn_exp2f)
#define FAST_EXP2(x) __builtin_amdgcn_exp2f(x)
#endif
#endif
#ifndef FAST_EXP2
#define FAST_EXP2(x) exp2f(x)
#endif

static __device__ __forceinline__ unsigned short f2bf(float x) {
    unsigned int u = __float_as_uint(x);
    return (unsigned short)((u + 0x7fffu + ((u >> 16) & 1u)) >> 16);  // RNE
}

// ---------- kernel 1: batch -> bf16 A, d_pos; zero rowsum slices + counter -
__global__ __launch_bounds__(256) void prep_kernel(
    const float* __restrict__ batch, const float* __restrict__ proxies,
    const int* __restrict__ labels, unsigned short* __restrict__ A,
    float* __restrict__ d_pos, float* __restrict__ rowsum,
    unsigned int* __restrict__ counter)
{
    if (threadIdx.x < 128) rowsum[blockIdx.x * 128 + threadIdx.x] = 0.f;
    if (blockIdx.x == 0 && threadIdx.x == 0) *counter = 0u;

    int wave = threadIdx.x >> 6, lane = threadIdx.x & 63;
    int sub = lane >> 5, c = lane & 31;
    int row = blockIdx.x * 8 + wave * 2 + sub;   // 0..1023
    float4 v = *(const float4*)(batch + (size_t)row * D + c * 4);
    float ss = v.x*v.x + v.y*v.y + v.z*v.z + v.w*v.w;
    #pragma unroll
    for (int m = 1; m < 32; m <<= 1) ss += __shfl_xor(ss, m, 64);
    float sc = 3.0f / fmaxf(sqrtf(ss), 1e-12f);
    ushort4 pk;
    pk.x = f2bf(v.x*sc); pk.y = f2bf(v.y*sc);
    pk.z = f2bf(v.z*sc); pk.w = f2bf(v.w*sc);
    *(ushort4*)(A + (size_t)row * D + c * 4) = pk;
    // d_pos in fp32: 18 - 2*(b.p_label)
    int lab = labels[row];
    float4 p4 = *(const float4*)(proxies + (size_t)lab * D + c * 4);
    float ps = p4.x*p4.x + p4.y*p4.y + p4.z*p4.z + p4.w*p4.w;
    #pragma unroll
    for (int m = 1; m < 32; m <<= 1) ps += __shfl_xor(ps, m, 64);
    float psc = 3.0f / fmaxf(sqrtf(ps), 1e-12f);
    float dt = (v.x*sc)*(p4.x*psc) + (v.y*sc)*(p4.y*psc)
             + (v.z*sc)*(p4.z*psc) + (v.w*sc)*(p4.w*psc);
    #pragma unroll
    for (int m = 1; m < 32; m <<= 1) dt += __shfl_xor(dt, m, 64);
    if (c == 0) d_pos[row] = 18.0f - 2.0f * dt;
}

// ---------- kernel 2: fused proxy-norm + outer-product GEMM + exp + final --
// 256 threads (4 waves), block = 128 proxies (two-pass staged into XOR-
// swizzled LDS bf16). m97-shape 4x4 OUTER PRODUCT per wave: 64 proxies
// (4 M-tiles, A streamed from LDS) x 64 batch rows (4 N-tiles, B streamed
// from global/L2), acc[4][4] f32x4 = 64 accumulator regs (AGPR-backed).
// K-loop kk=0..3: 4 ds_read_b128 + 4 global dwordx4 feed 16 MFMAs.
// Wave = (proxy-half ph, batch-half rh); 8 passes of 64 rows each.
// Reuse is structural (outer product) -- nothing needs to persist in regs
// across loops except acc, which MFMA pins by construction.
__global__ __launch_bounds__(256) void main_kernel(
    const float* __restrict__ proxies,
    const unsigned short* __restrict__ Abat,
    float* __restrict__ rowsum,          // [NSLICE][BS]
    const float* __restrict__ d_pos,
    float* __restrict__ out,
    unsigned int* __restrict__ counter)
{
    __shared__ unsigned short Plds[CH * D];   // 32 KB
    __shared__ float shf[4];
    __shared__ unsigned int is_last;
    const int tid = threadIdx.x;
    const int lane = tid & 63;
    const int wave = tid >> 6, quad = lane >> 4, l15 = lane & 15;
    const int chunk = blockIdx.x;

    // ---- staging: r = tid>>1 (0..127), h = tid&1 (64 floats each) --------
    {
        int r = tid >> 1, h = tid & 1;
        int pidx = chunk * CH + r;
        const float* src = proxies + (size_t)pidx * D + h * 64;
        float ss = 0.f;
        if (pidx < NP) {
            #pragma unroll
            for (int j = 0; j < 16; ++j) {
                float4 v = *(const float4*)(src + j * 4);
                ss += v.x*v.x + v.y*v.y + v.z*v.z + v.w*v.w;
            }
        }
        ss += __shfl_xor(ss, 1, 64);             // combine the two halves
        float sc = 3.0f / fmaxf(sqrtf(ss), 1e-12f);
        #pragma unroll
        for (int j = 0; j < 8; ++j) {
            u16x8 w = (u16x8){0,0,0,0,0,0,0,0};
            if (pidx < NP) {
                float4 a = *(const float4*)(src + j * 8);      // L2 hit
                float4 b = *(const float4*)(src + j * 8 + 4);
                w[0] = f2bf(a.x*sc); w[1] = f2bf(a.y*sc);
                w[2] = f2bf(a.z*sc); w[3] = f2bf(a.w*sc);
                w[4] = f2bf(b.x*sc); w[5] = f2bf(b.y*sc);
                w[6] = f2bf(b.z*sc); w[7] = f2bf(b.w*sc);
            }
            int cl = h * 8 + j;                  // 16B chunk index in row
            *(u16x8*)((char*)Plds + r * 256 + ((cl ^ (r & 15)) << 4)) = w;
        }
    }
    __syncthreads();

    const int ph = wave & 1;        // proxy half: M-tiles ph*4 .. ph*4+3
    const int rh = wave >> 1;       // batch half: rows rh*512 .. +512
    const float c1 = 2.0f * LOG2E, c0 = -18.0f * LOG2E;
    float* rs_base = rowsum + (size_t)(chunk & (NSLICE - 1)) * BS;

    #pragma unroll 1
    for (int p = 0; p < 8; ++p) {
        const int row0 = rh * 512 + p * 64;
        const unsigned short* ab = Abat + (size_t)(row0 + l15) * D + quad * 8;

        f32x4 acc[4][4];   // [mt][n] -- 64 regs, AGPR-backed by MFMA
        #pragma unroll
        for (int mt = 0; mt < 4; ++mt)
            #pragma unroll
            for (int n = 0; n < 4; ++n)
                acc[mt][n] = (f32x4){0.f, 0.f, 0.f, 0.f};

        #pragma unroll
        for (int kk = 0; kk < 4; ++kk) {
            // stream B: 4 N-tiles of 16 batch rows (global, L2-resident)
            bf16x8 Bf[4];
            #pragma unroll
            for (int n = 0; n < 4; ++n)
                Bf[n] = *(const bf16x8*)(ab + (size_t)n * 16 * D + kk * 32);
            // stream A: 4 M-tiles of 16 proxies (LDS, swizzled)
            f32x4 Af[4];
            #pragma unroll
            for (int mt = 0; mt < 4; ++mt) {
                int prow = ph * 64 + mt * 16 + l15;
                int cl = kk * 4 + quad;
                Af[mt] = *(const f32x4*)((const char*)Plds + prow * 256
                                         + ((cl ^ (prow & 15)) << 4));
            }
            // 16 MFMAs (outer product)
            #pragma unroll
            for (int mt = 0; mt < 4; ++mt)
                #pragma unroll
                for (int n = 0; n < 4; ++n)
                    acc[mt][n] = __builtin_amdgcn_mfma_f32_16x16x32_bf16(
                        __builtin_bit_cast(bf16x8, Af[mt]), Bf[n],
                        acc[mt][n], 0, 0, 0);
        }

        // epilogue: lane's batch col = row0 + n*16 + l15; proxy rows =
        // quad*4+i within each of 4 M-tiles -> 16 proxies in-lane, then
        // 2 shuffles fold the quads -> all 64 of this wave's proxies.
        #pragma unroll
        for (int n = 0; n < 4; ++n) {
            float rs = 0.f;
            #pragma unroll
            for (int mt = 0; mt < 4; ++mt) {
                float e0 = FAST_EXP2(fmaf(acc[mt][n][0], c1, c0));
                float e1 = FAST_EXP2(fmaf(acc[mt][n][1], c1, c0));
                float e2 = FAST_EXP2(fmaf(acc[mt][n][2], c1, c0));
                float e3 = FAST_EXP2(fmaf(acc[mt][n][3], c1, c0));
                rs += (e0 + e1) + (e2 + e3);
            }
            rs += __shfl_xor(rs, 16, 64);
            rs += __shfl_xor(rs, 32, 64);
            if (quad == 0)
                atomicAdd(rs_base + row0 + n * 16 + l15, rs);
        }
    }

    // ---- last-block-done: final lse + mean ------------------------------
    __syncthreads();
    if (tid == 0) {
        __threadfence();
        unsigned int old = __hip_atomic_fetch_add(counter, 1u,
                              __ATOMIC_ACQ_REL, __HIP_MEMORY_SCOPE_AGENT);
        is_last = (old == NCH - 1) ? 1u : 0u;
    }
    __syncthreads();
    if (is_last) {
        const float PADC = 96.0f * exp2f(-18.0f * LOG2E);  // zero-pad rows
        float accv = 0.f;
        #pragma unroll
        for (int i = 0; i < 4; ++i) {
            int row = tid * 4 + i;     // 0..1023
            float tot = 0.f;
            #pragma unroll
            for (int s = 0; s < NSLICE; ++s)
                tot += __hip_atomic_load(&rowsum[(size_t)s * BS + row],
                          __ATOMIC_RELAXED, __HIP_MEMORY_SCOPE_AGENT);
            float dp = d_pos[row];
            float neg = tot - expf(-dp) - PADC;            // drop own column
            accv += dp + logf(fmaxf(neg, 1e-37f));
        }
        #pragma unroll
        for (int m = 1; m < 64; m <<= 1) accv += __shfl_xor(accv, m, 64);
        if ((tid & 63) == 0) shf[tid >> 6] = accv;
        __syncthreads();
        if (tid == 0)
            out[0] = (shf[0] + shf[1] + shf[2] + shf[3]) * (1.0f / 1024.0f);
    }
}

extern "C" void kernel_launch(void* const* d_in, const int* in_sizes, int n_in,
                              void* d_out, int out_size, void* d_ws, size_t ws_size,
                              hipStream_t stream) {
    const float* batch   = (const float*)d_in[0];
    const float* proxies = (const float*)d_in[1];
    const int*   labels  = (const int*)d_in[2];
    float* out = (float*)d_out;

    char* ws = (char*)d_ws;
    unsigned short* A    = (unsigned short*)ws;                  //   262,144 B
    float* d_pos         = (float*)(ws + 262144);                //     4,096 B
    float* rowsum        = (float*)(ws + 266240);                //    65,536 B
    unsigned int* counter= (unsigned int*)(ws + 331776);         //         4 B

    prep_kernel<<<128, 256, 0, stream>>>(batch, proxies, labels, A, d_pos,
                                         rowsum, counter);
    main_kernel<<<NCH, 256, 0, stream>>>(proxies, A, rowsum, d_pos, out, counter);
}